// Round 1
// baseline (181.824 us; speedup 1.0000x reference)
//
#include <hip/hip_runtime.h>
#include <hip/hip_bf16.h>

typedef __attribute__((ext_vector_type(8)))  __bf16 bf16x8;
typedef __attribute__((ext_vector_type(16))) float  f32x16;

// Batched GEMM C[b] = A[b] @ B[b]^T,  A:[B,N1,D] B:[B,N2,D] C:[B,N1,N2], D=64.
// Write-bound (536 MB out vs 17 MB in). bf16 MFMA, fragments loaded straight
// from global (inputs are L2-resident; no LDS staging needed at K=64).

static __device__ inline bf16x8 to_bf16x8(const float4& a, const float4& b) {
    bf16x8 r;
    r[0] = (__bf16)a.x; r[1] = (__bf16)a.y; r[2] = (__bf16)a.z; r[3] = (__bf16)a.w;
    r[4] = (__bf16)b.x; r[5] = (__bf16)b.y; r[6] = (__bf16)b.z; r[7] = (__bf16)b.w;
    return r;
}

__global__ __launch_bounds__(256) void MatrixAttention_76149770158251_kernel(
    const float* __restrict__ A, const float* __restrict__ Bm,
    float* __restrict__ C, int N1, int N2, int D)
{
    const int lane = threadIdx.x & 63;
    const int wid  = threadIdx.x >> 6;      // 0..3
    const int wr   = wid >> 1;              // 2x2 wave grid
    const int wc   = wid & 1;
    const int b    = blockIdx.z;

    const int row0 = blockIdx.y * 128 + wr * 64;
    const int col0 = blockIdx.x * 128 + wc * 64;

    const float* __restrict__ Ab = A  + (size_t)b * N1 * D;
    const float* __restrict__ Bb = Bm + (size_t)b * N2 * D;
    float* __restrict__ Cb       = C  + (size_t)b * N1 * N2;

    const int lrow = lane & 31;           // row (A) / col (B) within 32-frag
    const int khalf = (lane >> 5) * 8;    // 0 or 8: which 8-elem K slice

    f32x16 acc[2][2];
#pragma unroll
    for (int i = 0; i < 2; ++i)
#pragma unroll
        for (int j = 0; j < 2; ++j) acc[i][j] = (f32x16)0.0f;

#pragma unroll
    for (int ks = 0; ks < 4; ++ks) {      // K = 64 = 4 * 16
        const int k = ks * 16 + khalf;
        bf16x8 af[2], bfr[2];
#pragma unroll
        for (int rb = 0; rb < 2; ++rb) {
            const float* p = Ab + (size_t)(row0 + rb * 32 + lrow) * D + k;
            float4 v0 = *(const float4*)(p);
            float4 v1 = *(const float4*)(p + 4);
            af[rb] = to_bf16x8(v0, v1);
        }
#pragma unroll
        for (int cb = 0; cb < 2; ++cb) {
            const float* p = Bb + (size_t)(col0 + cb * 32 + lrow) * D + k;
            float4 v0 = *(const float4*)(p);
            float4 v1 = *(const float4*)(p + 4);
            bfr[cb] = to_bf16x8(v0, v1);
        }
#pragma unroll
        for (int rb = 0; rb < 2; ++rb)
#pragma unroll
            for (int cb = 0; cb < 2; ++cb)
                acc[rb][cb] = __builtin_amdgcn_mfma_f32_32x32x16_bf16(
                    af[rb], bfr[cb], acc[rb][cb], 0, 0, 0);
    }

    // C/D layout (verified m74/m101): col = lane&31, row = (reg&3)+8*(reg>>2)+4*(lane>>5)
#pragma unroll
    for (int rb = 0; rb < 2; ++rb)
#pragma unroll
        for (int cb = 0; cb < 2; ++cb) {
            const int col   = col0 + cb * 32 + (lane & 31);
            const int rbase = row0 + rb * 32 + 4 * (lane >> 5);
#pragma unroll
            for (int v = 0; v < 16; ++v) {
                const int row = rbase + (v & 3) + 8 * (v >> 2);
                Cb[(size_t)row * N2 + col] = acc[rb][cb][v];
            }
        }
}

extern "C" void kernel_launch(void* const* d_in, const int* in_sizes, int n_in,
                              void* d_out, int out_size, void* d_ws, size_t ws_size,
                              hipStream_t stream) {
    const float* m1 = (const float*)d_in[0];
    const float* m2 = (const float*)d_in[1];
    float* out = (float*)d_out;

    const int B = 8, N1 = 4096, N2 = 4096, D = 64;
    dim3 grid(N2 / 128, N1 / 128, B);
    dim3 block(256);
    MatrixAttention_76149770158251_kernel<<<grid, block, 0, stream>>>(m1, m2, out, N1, N2, D);
}